// Round 8
// baseline (1862.510 us; speedup 1.0000x reference)
//
#include <hip/hip_runtime.h>

#define TT 256
#define VV 5000
#define NC4 1250
#define BEAMW 16
#define WASR 0.7f
#define WLM 0.3f
#define SOS_TOK 1
#define LK 128          // list capacity (histogram-capped)
#define FCAP 512
#define COMMW 2048

// ws float offsets
#define OFF_LSTAT4 0                   // float4[VV] {m, logS, bsel_bits, lbnd}
#define OFF_AM     (4*VV)
#define OFF_ALS    (4*VV + TT)
#define OFF_ATH    (4*VV + 2*TT)
#define OFF_ABND   (4*VV + 3*TT)
#define OFF_COMM   (4*VV + 4*TT)       // COMMW uint words
#define OFF_LISTS  (OFF_COMM + COMMW)  // float2 L[VV][LK] then A[TT][LK]

// comm uint-word layout (relative to OFF_COMM):
//  [17]              phase-1 counter (16 per step)
//  [18]              redo counter (16 per redo epoch)
//  [32 + b*32 + 2k]  SURV_b phase-1: ull pair (val | flat<<32), k=0..15
//  [544 + b]         BNDS[b] bound bits
//  [592 + b*32 + 2k] SURV_b redo: ull pairs
static inline size_t ws_need_floats() {
  return (size_t)OFF_LISTS + 2ull * (VV + TT) * LK;
}

__device__ __forceinline__ int bin16(float m, float x) {
  float y   = __fsub_rn(m, x);
  float y16 = __fmul_rn(y, 16.0f);
  int bb = (int)y16;
  return bb < 0 ? 0 : (bb > 255 ? 255 : bb);
}

__device__ __forceinline__ unsigned int fkey(float v) {
  unsigned int u = __float_as_uint(v);
  return (u & 0x80000000u) ? ~u : (u | 0x80000000u);
}

__device__ __forceinline__ float cand_val(float s, float a, float am, float als,
                                          float x, float mB, float lsB) {
  float av = __fmul_rn(WASR, __fsub_rn(__fsub_rn(a, am), als));
  float lv = __fmul_rn(WLM,  __fsub_rn(__fsub_rn(x, mB), lsB));
  return __fadd_rn(__fadd_rn(s, av), lv);
}

__device__ __forceinline__ float bitonic64_desc_val(float v, int lane) {
#pragma unroll
  for (int kk = 2; kk <= 64; kk <<= 1)
#pragma unroll
    for (int j = kk >> 1; j > 0; j >>= 1) {
      float o = __shfl_xor(v, j, 64);
      bool keepMax = (((lane & kk) == 0) == ((lane & j) == 0));
      v = keepMax ? fmaxf(v, o) : fminf(v, o);
    }
  return v;
}

__device__ __forceinline__ void bitonic64_desc_pair(float& bv, int& bi, int lane) {
#pragma unroll
  for (int kk = 2; kk <= 64; kk <<= 1)
#pragma unroll
    for (int j = kk >> 1; j > 0; j >>= 1) {
      float ov = __shfl_xor(bv, j, 64);
      int   oi = __shfl_xor(bi, j, 64);
      bool keepTop = (((lane & kk) == 0) == ((lane & j) == 0));
      bool mineBetter = (bv > ov) || (bv == ov && bi < oi);
      if (keepTop != mineBetter) { bv = ov; bi = oi; }
    }
}

// ---------------- prep: row stats + θ-capped shortlists ----------
__global__ __launch_bounds__(256) void prep_kernel(
    const float* __restrict__ asr, const float* __restrict__ lm,
    float* __restrict__ ws, int build)
{
  __shared__ float sm[8];
  __shared__ int   hist[256];
  __shared__ int   s_bsel;
  __shared__ int   s_cnt;

  const int row = blockIdx.x;
  const bool is_lm = (row < VV);
  const int t = row - VV;
  const int tid = (int)threadIdx.x;

  if (row == 0) {
    for (int k = tid; k < COMMW; k += 256)
      ((unsigned int*)(ws + OFF_COMM))[k] = 0u;
  }

  const float* src = is_lm ? (lm + (size_t)row * VV) : (asr + (size_t)t * VV);
  const float4* s4 = (const float4*)src;

  float4 x[5];
  float m = -INFINITY;
#pragma unroll
  for (int k = 0; k < 5; ++k) {
    int c = tid + 256 * k;
    if (c < NC4) {
      x[k] = s4[c];
      m = fmaxf(m, fmaxf(fmaxf(x[k].x, x[k].y), fmaxf(x[k].z, x[k].w)));
    }
  }
#pragma unroll
  for (int j = 1; j < 64; j <<= 1) m = fmaxf(m, __shfl_xor(m, j, 64));
  if ((tid & 63) == 0) sm[tid >> 6] = m;
  __syncthreads();
  m = fmaxf(fmaxf(sm[0], sm[1]), fmaxf(sm[2], sm[3]));
  __syncthreads();

  float ssum = 0.f;
#pragma unroll
  for (int k = 0; k < 5; ++k) {
    int c = tid + 256 * k;
    if (c < NC4) {
      ssum += expf(x[k].x - m);
      ssum += expf(x[k].y - m);
      ssum += expf(x[k].z - m);
      ssum += expf(x[k].w - m);
    }
  }
#pragma unroll
  for (int j = 1; j < 64; j <<= 1) ssum += __shfl_xor(ssum, j, 64);
  if ((tid & 63) == 0) sm[4 + (tid >> 6)] = ssum;
  __syncthreads();
  ssum = (sm[4] + sm[5]) + (sm[6] + sm[7]);
  const float logS = logf(ssum);

  if (!build) {
    if (tid == 0) {
      if (is_lm) ((float4*)(ws + OFF_LSTAT4))[row] = make_float4(m, logS, __int_as_float(0), 0.f);
      else { ws[OFF_AM + t] = m; ws[OFF_ALS + t] = logS; }
    }
    return;
  }
  if (!is_lm && tid == 0) { ws[OFF_AM + t] = m; ws[OFF_ALS + t] = logS; }

  hist[tid] = 0;
  __syncthreads();
#pragma unroll
  for (int k = 0; k < 5; ++k) {
    int c = tid + 256 * k;
    if (c < NC4) {
      float vv[4] = {x[k].x, x[k].y, x[k].z, x[k].w};
#pragma unroll
      for (int j = 0; j < 4; ++j) atomicAdd(&hist[bin16(m, vv[j])], 1);
    }
  }
  __syncthreads();
  if (tid == 0) {
    int c = 0, bsel = 0;
    for (; bsel < 256; ++bsel) {
      int nc = c + hist[bsel];
      if (nc <= LK) c = nc; else break;
    }
    s_bsel = bsel;
    s_cnt = 0;
  }
  __syncthreads();
  const int bsel = s_bsel;
  const float wgt = is_lm ? WLM : WASR;
  float2* Llists = (float2*)(ws + OFF_LISTS);
  float2* dst = is_lm ? (Llists + (size_t)row * LK)
                      : (Llists + (size_t)VV * LK + (size_t)t * LK);
#pragma unroll
  for (int k = 0; k < 5; ++k) {
    int c = tid + 256 * k;
    if (c < NC4) {
      float vv[4] = {x[k].x, x[k].y, x[k].z, x[k].w};
#pragma unroll
      for (int j = 0; j < 4; ++j) {
        if (bin16(m, vv[j]) < bsel) {
          int p = atomicAdd(&s_cnt, 1);
          if (p < LK) {
            float sv = __fmul_rn(wgt, __fsub_rn(__fsub_rn(vv[j], m), logS));
            dst[p] = make_float2(sv, __int_as_float(c * 4 + j));
          }
        }
      }
    }
  }
  __syncthreads();
  const int cnt = s_cnt;
  const bool ovf = (cnt == 0);
  for (int p = cnt + tid; p < LK; p += 256)
    dst[p] = make_float2(-1e30f, __int_as_float(0x7FFFFFFF));

  if (tid == 0) {
    float theta = __fsub_rn(m, (float)bsel * 0.0625f);
    float bnd = ovf ? INFINITY : __fmul_rn(wgt, __fsub_rn(__fsub_rn(theta, m), logS));
    int bselO = ovf ? 0 : bsel;
    if (is_lm) ((float4*)(ws + OFF_LSTAT4))[row] = make_float4(m, logS, __int_as_float(bselO), bnd);
    else { ws[OFF_ATH + t] = __int_as_float(bselO); ws[OFF_ABND + t] = bnd; }
  }
}

// ---------------- multi-WG beam search: 16 same-XCD workers ----------
__global__ __launch_bounds__(256) void beam_mw(
    const float* __restrict__ asr, const float* __restrict__ lm,
    float* __restrict__ ws, float* __restrict__ out)
{
  const int gb = (int)blockIdx.x;
  // worker election: one WG per 8 consecutive blockIdx values. Under the
  // de-facto round-robin blockIdx->XCD mapping, all 16 workers land on the
  // same XCD (L2-local comm). Correct regardless of mapping.
  if ((gb & 7) != 0) return;
  const int b = gb >> 3;
  const int tid = (int)threadIdx.x;
  const int lane = tid & 63;
  const int w = tid >> 6;

  const float2* __restrict__ Llists = (const float2*)(ws + OFF_LISTS);
  const float2* __restrict__ Alists = Llists + (size_t)VV * LK;
  const float4* __restrict__ lstat4 = (const float4*)(ws + OFF_LSTAT4);
  unsigned int* C = (unsigned int*)(ws + OFF_COMM);

  __shared__ float2 s_alist[2][LK];
  __shared__ float s_cv[FCAP];
  __shared__ int   s_ct[FCAP];
  __shared__ unsigned long long s_key[256];
  __shared__ unsigned long long s_k2[64];
  __shared__ float s_sv2[64];
  __shared__ int   s_si2[64];
  __shared__ float s_selv[BEAMW];
  __shared__ int   s_seli[BEAMW];
  __shared__ float s_ftau[4];
  __shared__ int   s_fcnt;
  __shared__ int   s_redo;
  __shared__ unsigned short s_toks[TT * BEAMW];   // beam-0 worker only
  __shared__ unsigned char  s_bps[TT * BEAMW];

  float s = (b == 0) ? 0.0f : -1e30f;
  int last = SOS_TOK;
  float4 lst = lstat4[SOS_TOK];
  int redo_epoch = 0;
  int cur = 0;

  if (tid < LK) s_alist[0][tid] = Alists[tid];   // A-list for t=0
  __syncthreads();

  // local merge of 256 pooled survivors (s_cv/s_ct) -> s_selv/s_seli
  auto merge256 = [&]() {
    float v = s_cv[tid]; int fl = s_ct[tid];
    unsigned long long key = ((unsigned long long)fkey(v) << 17) | (unsigned)(131071 - fl);
    s_key[tid] = key;
    __syncthreads();
    int segbase = tid & ~63;
    int r = 0;
    for (int j = 0; j < 64; ++j) r += (s_key[segbase + j] > key) ? 1 : 0;
    if (r < BEAMW) {
      int slot = ((tid >> 6) << 4) | r;
      s_k2[slot] = key; s_sv2[slot] = v; s_si2[slot] = fl;
    }
    __syncthreads();
    if (tid < 64) {
      unsigned long long k2 = s_k2[tid];
      int r2 = 0;
      for (int j = 0; j < 64; ++j) r2 += (s_k2[j] > k2) ? 1 : 0;
      if (r2 < BEAMW) { s_selv[r2] = s_sv2[tid]; s_seli[r2] = s_si2[tid]; }
    }
    __syncthreads();
  };

  for (int t = 0; t < TT; ++t) {
    const float am   = ws[OFF_AM + t];
    const float als  = ws[OFF_ALS + t];
    const float abnd = ws[OFF_ABND + t];
    const float mB = lst.x, lsB = lst.y, lbnd = lst.w;
    const int bselL = __float_as_int(lst.z);
    const float bound = __fadd_rn(__fadd_rn(s, abnd), lbnd) + 1e-3f;

    // prefetch next step's A-list (statically indexed; off critical path)
    float2 ga;
    {
      int tn = (t + 1 < TT) ? (t + 1) : t;
      if (tid < LK) ga = Alists[(size_t)tn * LK + tid];
    }

    // ---- EVAL: 256 candidate slots (A: 0..127 from LDS, L: 128..255) ----
    {
      float cv = -INFINITY; int ct = 0;
      int j = ((w & 1) << 6) | lane;
      if (w < 2) {
        float2 ae = s_alist[cur][j];
        int tok = __float_as_int(ae.y);
        bool valid = (ae.x > -9e29f);
        float xr = lm[(size_t)last * VV + (valid ? tok : 0)];
        if (valid) {
          ct = tok;
          bool inL = (bin16(mB, xr) < bselL);   // dedupe: token also in L-list
          if (!inL) {
            float svr = __fmul_rn(WLM, __fsub_rn(__fsub_rn(xr, mB), lsB));
            cv = __fadd_rn(__fadd_rn(s, ae.x), svr);
          }
        }
      } else {
        float2 le = Llists[(size_t)last * LK + j];
        int tok = __float_as_int(le.y);
        bool valid = (le.x > -9e29f);
        float ar = asr[(size_t)t * VV + (valid ? tok : 0)];
        if (valid) {
          ct = tok;
          float avr = __fmul_rn(WASR, __fsub_rn(__fsub_rn(ar, am), als));
          cv = __fadd_rn(__fadd_rn(s, avr), le.x);
        }
      }
      s_cv[tid] = cv; s_ct[tid] = ct;
    }
    __syncthreads();
    if (tid < LK) s_alist[cur ^ 1][tid] = ga;   // write prefetched A-list

    // ---- per-beam exact top-16 of 256 (two-stage rank) ----
    {
      float v = s_cv[tid]; int tok = s_ct[tid];
      bool inval = !(v > -INFINITY);
      int tkk = inval ? (5000 + tid) : tok;
      unsigned long long key = ((unsigned long long)fkey(v) << 13) | (unsigned)(8191 - tkk);
      s_key[tid] = key;
      __syncthreads();
      int segbase = tid & ~63;
      int r = 0;
      for (int j = 0; j < 64; ++j) r += (s_key[segbase + j] > key) ? 1 : 0;
      if (r < BEAMW) {
        int slot = ((tid >> 6) << 4) | r;
        s_k2[slot] = key; s_sv2[slot] = v; s_si2[slot] = inval ? -1 : tok;
      }
      __syncthreads();
      if (tid < 64) {
        unsigned long long k2 = s_k2[tid];
        int r2 = 0;
        for (int j = 0; j < 64; ++j) r2 += (s_k2[j] > k2) ? 1 : 0;
        if (r2 < BEAMW) {
          int tk2 = s_si2[tid];
          s_selv[r2] = s_sv2[tid];
          s_seli[r2] = (tk2 < 0) ? (80000 + b * BEAMW + r2) : (b * VV + tk2);
        }
      }
      __syncthreads();
    }

    // ---- publish 16 pairs + bound; release counter-add; acquire poll ----
    if (tid == 0) {
      unsigned long long* S = (unsigned long long*)(C + 32 + b * 32);
      for (int k = 0; k < BEAMW; ++k) {
        unsigned long long pk = ((unsigned long long)(unsigned int)s_seli[k] << 32)
                              | (unsigned long long)__float_as_uint(s_selv[k]);
        __hip_atomic_store(&S[k], pk, __ATOMIC_RELAXED, __HIP_MEMORY_SCOPE_AGENT);
      }
      __hip_atomic_store(&C[544 + b], __float_as_uint(bound), __ATOMIC_RELAXED, __HIP_MEMORY_SCOPE_AGENT);
      __hip_atomic_fetch_add(&C[17], 1u, __ATOMIC_RELEASE, __HIP_MEMORY_SCOPE_AGENT);
      int gd = 0;
      while (__hip_atomic_load(&C[17], __ATOMIC_ACQUIRE, __HIP_MEMORY_SCOPE_AGENT) < (unsigned)(BEAMW * (t + 1))) {
        __builtin_amdgcn_s_sleep(2);
        if (++gd > 4000000) break;
      }
    }
    __syncthreads();

    // ---- read all 256 survivors; local redundant merge ----
    {
      const unsigned long long* S = (const unsigned long long*)(C + 32 + (tid >> 4) * 32);
      unsigned long long pk = __hip_atomic_load(&S[tid & 15], __ATOMIC_RELAXED, __HIP_MEMORY_SCOPE_AGENT);
      s_cv[tid] = __uint_as_float((unsigned int)pk);
      s_ct[tid] = (int)(unsigned int)(pk >> 32);
    }
    __syncthreads();
    merge256();

    // ---- redundant redo decision ----
    {
      float tau16 = s_selv[BEAMW - 1];
      bool c16 = false;
      if (tid < BEAMW) {
        float bq = __uint_as_float(__hip_atomic_load(&C[544 + tid], __ATOMIC_RELAXED, __HIP_MEMORY_SCOPE_AGENT));
        c16 = (bq > tau16);
      }
      unsigned long long mk = __ballot(c16);
      if (tid == 0) s_redo = (mk != 0ull) ? 1 : 0;
    }
    __syncthreads();

    // ---- rare: exact per-beam full scan + re-merge via redo buffer ----
    if (s_redo) {
      redo_epoch++;
      if (tid == 0) s_fcnt = 0;
      const float4* A4 = (const float4*)(asr + (size_t)t * VV);
      const float4* L4 = (const float4*)(lm + (size_t)last * VV);
      float chm[5]; float tm = -INFINITY;
#pragma unroll
      for (int q = 0; q < 5; ++q) {
        int c = tid + (q << 8);
        float cm = -INFINITY;
        if (c < NC4) {
          float4 a4 = A4[c]; float4 l4 = L4[c];
          float v0 = cand_val(s, a4.x, am, als, l4.x, mB, lsB);
          float v1 = cand_val(s, a4.y, am, als, l4.y, mB, lsB);
          float v2 = cand_val(s, a4.z, am, als, l4.z, mB, lsB);
          float v3 = cand_val(s, a4.w, am, als, l4.w, mB, lsB);
          cm = fmaxf(fmaxf(v0, v1), fmaxf(v2, v3));
        }
        chm[q] = cm; tm = fmaxf(tm, cm);
      }
      float vs = bitonic64_desc_val(tm, lane);
      if (lane == 15) s_ftau[w] = vs;
      __syncthreads();
      float tg = fmaxf(fmaxf(s_ftau[0], s_ftau[1]), fmaxf(s_ftau[2], s_ftau[3]));
#pragma unroll
      for (int q = 0; q < 5; ++q) {
        if (chm[q] >= tg) {
          int c = tid + (q << 8);
          float4 a4 = A4[c]; float4 l4 = L4[c];
          float ar4[4] = {a4.x, a4.y, a4.z, a4.w};
          float lr4[4] = {l4.x, l4.y, l4.z, l4.w};
#pragma unroll
          for (int i = 0; i < 4; ++i) {
            float v = cand_val(s, ar4[i], am, als, lr4[i], mB, lsB);
            if (v >= tg) {
              int p = atomicAdd(&s_fcnt, 1);
              if (p < FCAP) { s_cv[p] = v; s_ct[p] = c * 4 + i; }
            }
          }
        }
      }
      __syncthreads();
      int n = s_fcnt; if (n > FCAP) n = FCAP;
      {
        float v0 = (tid < n) ? s_cv[tid] : -INFINITY;
        int   t0 = (tid < n) ? s_ct[tid] : 0;
        float v1 = (tid + 256 < n) ? s_cv[tid + 256] : -INFINITY;
        int   t1 = (tid + 256 < n) ? s_ct[tid + 256] : 0;
        unsigned long long k0 = ((unsigned long long)fkey(v0) << 13) | (unsigned)(8191 - t0);
        unsigned long long k1 = ((unsigned long long)fkey(v1) << 13) | (unsigned)(8191 - t1);
        int r0 = 0, r1 = 0;
        for (int j = 0; j < n; ++j) {
          unsigned long long kj = ((unsigned long long)fkey(s_cv[j]) << 13) | (unsigned)(8191 - s_ct[j]);
          r0 += (kj > k0) ? 1 : 0;
          r1 += (kj > k1) ? 1 : 0;
        }
        __syncthreads();
        if (tid < n && r0 < BEAMW)       { s_selv[r0] = v0; s_seli[r0] = b * VV + t0; }
        if (tid + 256 < n && r1 < BEAMW) { s_selv[r1] = v1; s_seli[r1] = b * VV + t1; }
      }
      __syncthreads();

      if (tid == 0) {
        unsigned long long* R = (unsigned long long*)(C + 592 + b * 32);
        for (int k = 0; k < BEAMW; ++k) {
          unsigned long long pk = ((unsigned long long)(unsigned int)s_seli[k] << 32)
                                | (unsigned long long)__float_as_uint(s_selv[k]);
          __hip_atomic_store(&R[k], pk, __ATOMIC_RELAXED, __HIP_MEMORY_SCOPE_AGENT);
        }
        __hip_atomic_fetch_add(&C[18], 1u, __ATOMIC_RELEASE, __HIP_MEMORY_SCOPE_AGENT);
        int gd = 0;
        while (__hip_atomic_load(&C[18], __ATOMIC_ACQUIRE, __HIP_MEMORY_SCOPE_AGENT) < (unsigned)(BEAMW * redo_epoch)) {
          __builtin_amdgcn_s_sleep(2);
          if (++gd > 4000000) break;
        }
      }
      __syncthreads();
      {
        const unsigned long long* R = (const unsigned long long*)(C + 592 + (tid >> 4) * 32);
        unsigned long long pk = __hip_atomic_load(&R[tid & 15], __ATOMIC_RELAXED, __HIP_MEMORY_SCOPE_AGENT);
        s_cv[tid] = __uint_as_float((unsigned int)pk);
        s_ct[tid] = (int)(unsigned int)(pk >> 32);
      }
      __syncthreads();
      merge256();
    }

    // ---- next state (each WG local) + beam-0 history ----
    if (b == 0 && tid < BEAMW) {
      int fl = s_seli[tid];
      int bp = fl / VV; int tok = fl - bp * VV;
      s_toks[t * BEAMW + tid] = (unsigned short)tok;
      s_bps[t * BEAMW + tid]  = (unsigned char)bp;
    }
    {
      float nv = s_selv[b]; int fl = s_seli[b];
      int bp = fl / VV; int tok = fl - bp * VV;
      s = nv; last = tok;
    }
    lst = lstat4[last];
    __syncthreads();
    cur ^= 1;
  }

  // ---- output (beam-0 worker) ----
  if (b == 0 && tid < BEAMW) {
    out[tid] = s_selv[tid];
    int ptr = tid;
    for (int tt = TT - 1; tt >= 0; --tt) {
      int tok = (int)s_toks[tt * BEAMW + ptr];
      out[BEAMW + tid * TT + tt] = (float)tok;
      ptr = (int)s_bps[tt * BEAMW + ptr];
    }
  }
}

// ---------------- fallback: single-WG full-scan kernel (ws too small) ----
__global__ __launch_bounds__(1024, 4) void beam_slow(
    const float* __restrict__ asr, const float* __restrict__ lm,
    const float* __restrict__ ws, float* __restrict__ out)
{
  __shared__ float s_scores[BEAMW];
  __shared__ int   s_last[BEAMW];
  __shared__ float s_lmm[BEAMW], s_lmls[BEAMW];
  __shared__ float s_tau[BEAMW];
  __shared__ float s_bufval[FCAP];
  __shared__ int   s_bufidx[FCAP];
  __shared__ int   s_cnt;
  __shared__ unsigned short s_toks[TT * BEAMW];
  __shared__ unsigned char  s_bps[TT * BEAMW];

  const int tid = (int)threadIdx.x;
  const int lane = tid & 63;
  const int w = tid >> 6;
  const float4* __restrict__ lstat4 = (const float4*)(ws + OFF_LSTAT4);

  if (tid < BEAMW) {
    s_scores[tid] = (tid == 0) ? 0.0f : -1e30f;
    s_last[tid] = SOS_TOK;
    float4 st = lstat4[SOS_TOK];
    s_lmm[tid] = st.x; s_lmls[tid] = st.y;
  }
  if (tid == 0) s_cnt = 0;
  __syncthreads();

  for (int t = 0; t < TT; ++t) {
    const float s = s_scores[w];
    const float mB = s_lmm[w], lsB = s_lmls[w];
    const int lastb = s_last[w];
    const float am = ws[OFF_AM + t], als = ws[OFF_ALS + t];
    const float4* __restrict__ L4p = (const float4*)(lm + (size_t)lastb * VV);
    const float4* __restrict__ A4p = (const float4*)(asr + (size_t)t * VV);

    float chm[20]; float rowm = -INFINITY;
#pragma unroll
    for (int k = 0; k < 20; ++k) {
      int c = lane + 64 * k;
      bool ok = (c < NC4);
      int cc = ok ? c : 0;
      float4 A4 = A4p[cc]; float4 L4 = L4p[cc];
      float vx = cand_val(s, A4.x, am, als, L4.x, mB, lsB);
      float vy = cand_val(s, A4.y, am, als, L4.y, mB, lsB);
      float vz = cand_val(s, A4.z, am, als, L4.z, mB, lsB);
      float vw = cand_val(s, A4.w, am, als, L4.w, mB, lsB);
      float cm = fmaxf(fmaxf(vx, vy), fmaxf(vz, vw));
      if (!ok) cm = -INFINITY;
      chm[k] = cm; rowm = fmaxf(rowm, cm);
    }
    {
      float v = bitonic64_desc_val(rowm, lane);
      if (lane == 15) s_tau[w] = v;
    }
    if (tid == 0) s_cnt = 0;
    __syncthreads();

    float tg = s_tau[lane & 15];
#pragma unroll
    for (int j = 1; j <= 8; j <<= 1) tg = fmaxf(tg, __shfl_xor(tg, j, 64));

#pragma unroll
    for (int k = 0; k < 20; ++k) {
      if (chm[k] >= tg) {
        int c = lane + 64 * k;
        float4 A4 = A4p[c]; float4 L4 = L4p[c];
        float ar4[4] = {A4.x, A4.y, A4.z, A4.w};
        float lr4[4] = {L4.x, L4.y, L4.z, L4.w};
#pragma unroll
        for (int i = 0; i < 4; ++i) {
          float v = cand_val(s, ar4[i], am, als, lr4[i], mB, lsB);
          if (v >= tg) {
            int p = atomicAdd(&s_cnt, 1);
            if (p < FCAP) { s_bufval[p] = v; s_bufidx[p] = w * VV + c * 4 + i; }
          }
        }
      }
    }
    __syncthreads();

    if (w == 0) {
      int n = s_cnt; if (n > FCAP) n = FCAP;
      if (n <= 64) {
        float bv = (lane < n) ? s_bufval[lane] : -INFINITY;
        int   bi = (lane < n) ? s_bufidx[lane] : 0x7FFFFFFF;
        bitonic64_desc_pair(bv, bi, lane);
        if (lane < BEAMW) {
          int flat = bi;
          int bb = flat / VV; int tok = flat - bb * VV;
          float4 st = lstat4[tok];
          s_scores[lane] = bv; s_last[lane] = tok;
          s_lmm[lane] = st.x; s_lmls[lane] = st.y;
          s_toks[t * BEAMW + lane] = (unsigned short)tok;
          s_bps[t * BEAMW + lane] = (unsigned char)bb;
        }
      } else {
        float pv = -INFINITY; int pi = 0x7FFFFFFF;
        for (int it = 0; it < BEAMW; ++it) {
          float cvv = -INFINITY; int cii = 0x7FFFFFFF;
          for (int k2 = 0; k2 < FCAP / 64; ++k2) {
            int p = lane + 64 * k2;
            if (p < n) {
              float vv2 = s_bufval[p]; int ii2 = s_bufidx[p];
              bool lessPrev = (it == 0) || (vv2 < pv) || (vv2 == pv && ii2 > pi);
              bool better = (vv2 > cvv) || (vv2 == cvv && ii2 < cii);
              if (lessPrev && better) { cvv = vv2; cii = ii2; }
            }
          }
          for (int j = 1; j < 64; j <<= 1) {
            float ov = __shfl_xor(cvv, j, 64); int oi = __shfl_xor(cii, j, 64);
            bool ob = (ov > cvv) || (ov == cvv && oi < cii);
            if (ob) { cvv = ov; cii = oi; }
          }
          if (lane == 0) {
            int bb = cii / VV; int tok = cii - bb * VV;
            float4 st = lstat4[tok];
            s_scores[it] = cvv; s_last[it] = tok;
            s_lmm[it] = st.x; s_lmls[it] = st.y;
            s_toks[t * BEAMW + it] = (unsigned short)tok;
            s_bps[t * BEAMW + it] = (unsigned char)bb;
          }
          pv = cvv; pi = cii;
        }
      }
    }
    __syncthreads();
  }

  if (tid < BEAMW) {
    out[tid] = s_scores[tid];
    int ptr = tid;
    for (int t = TT - 1; t >= 0; --t) {
      int tok = (int)s_toks[t * BEAMW + ptr];
      out[BEAMW + tid * TT + t] = (float)tok;
      ptr = (int)s_bps[t * BEAMW + ptr];
    }
  }
}

extern "C" void kernel_launch(void* const* d_in, const int* in_sizes, int n_in,
                              void* d_out, int out_size, void* d_ws, size_t ws_size,
                              hipStream_t stream) {
  const float* asr = (const float*)d_in[0];
  const float* lm  = (const float*)d_in[1];
  float* out = (float*)d_out;
  float* ws  = (float*)d_ws;

  int build = (ws_size >= ws_need_floats() * sizeof(float)) ? 1 : 0;
  hipLaunchKernelGGL(prep_kernel, dim3(VV + TT), dim3(256), 0, stream, asr, lm, ws, build);
  if (build)
    hipLaunchKernelGGL(beam_mw, dim3(BEAMW * 8), dim3(256), 0, stream, asr, lm, ws, out);
  else
    hipLaunchKernelGGL(beam_slow, dim3(1), dim3(1024), 0, stream, asr, lm, ws, out);
}

// Round 9
// 1405.267 us; speedup vs baseline: 1.3254x; 1.3254x over previous
//
#include <hip/hip_runtime.h>

#define TT 256
#define VV 5000
#define NC4 1250
#define BEAMW 16
#define WASR 0.7f
#define WLM 0.3f
#define SOS_TOK 1
#define LK 128          // list capacity (histogram-capped)
#define FCAP 512
#define COMMW 8192

// ws float offsets
#define OFF_LSTAT4 0                   // float4[VV] {m, logS, bsel_bits, lbnd}
#define OFF_AM     (4*VV)
#define OFF_ALS    (4*VV + TT)
#define OFF_ATH    (4*VV + 2*TT)
#define OFF_ABND   (4*VV + 3*TT)
#define OFF_COMM   (4*VV + 4*TT)       // COMMW uint words
#define OFF_LISTS  (OFF_COMM + COMMW)  // float2 L[VV][LK] then A[TT][LK]

// comm layout in ULL units (D = (ull*)(ws+OFF_COMM)):
//  D[64  + par*512 + b*32 + k]  phase-1 slot: k<16 pairs, k==16 bound word
//  D[1088 + par*512 + b*32 + k] redo slot
// pair: [63:54] tag (= t+1) | [53:32] flat | [31:0] val bits
// bound word: [63:54] tag | [31:0] bound bits
static inline size_t ws_need_floats() {
  return (size_t)OFF_LISTS + 2ull * (VV + TT) * LK;
}

__device__ __forceinline__ int bin16(float m, float x) {
  float y   = __fsub_rn(m, x);
  float y16 = __fmul_rn(y, 16.0f);
  int bb = (int)y16;
  return bb < 0 ? 0 : (bb > 255 ? 255 : bb);
}

__device__ __forceinline__ unsigned int fkey(float v) {
  unsigned int u = __float_as_uint(v);
  return (u & 0x80000000u) ? ~u : (u | 0x80000000u);
}

__device__ __forceinline__ float cand_val(float s, float a, float am, float als,
                                          float x, float mB, float lsB) {
  float av = __fmul_rn(WASR, __fsub_rn(__fsub_rn(a, am), als));
  float lv = __fmul_rn(WLM,  __fsub_rn(__fsub_rn(x, mB), lsB));
  return __fadd_rn(__fadd_rn(s, av), lv);
}

__device__ __forceinline__ float bitonic64_desc_val(float v, int lane) {
#pragma unroll
  for (int kk = 2; kk <= 64; kk <<= 1)
#pragma unroll
    for (int j = kk >> 1; j > 0; j >>= 1) {
      float o = __shfl_xor(v, j, 64);
      bool keepMax = (((lane & kk) == 0) == ((lane & j) == 0));
      v = keepMax ? fmaxf(v, o) : fminf(v, o);
    }
  return v;
}

__device__ __forceinline__ void bitonic64_desc_pair(float& bv, int& bi, int lane) {
#pragma unroll
  for (int kk = 2; kk <= 64; kk <<= 1)
#pragma unroll
    for (int j = kk >> 1; j > 0; j >>= 1) {
      float ov = __shfl_xor(bv, j, 64);
      int   oi = __shfl_xor(bi, j, 64);
      bool keepTop = (((lane & kk) == 0) == ((lane & j) == 0));
      bool mineBetter = (bv > ov) || (bv == ov && bi < oi);
      if (keepTop != mineBetter) { bv = ov; bi = oi; }
    }
}

// ---------------- prep: row stats + θ-capped shortlists ----------
__global__ __launch_bounds__(256) void prep_kernel(
    const float* __restrict__ asr, const float* __restrict__ lm,
    float* __restrict__ ws, int build)
{
  __shared__ float sm[8];
  __shared__ int   hist[256];
  __shared__ int   s_bsel;
  __shared__ int   s_cnt;

  const int row = blockIdx.x;
  const bool is_lm = (row < VV);
  const int t = row - VV;
  const int tid = (int)threadIdx.x;

  if (row == 0) {
    for (int k = tid; k < COMMW; k += 256)
      ((unsigned int*)(ws + OFF_COMM))[k] = 0u;
  }

  const float* src = is_lm ? (lm + (size_t)row * VV) : (asr + (size_t)t * VV);
  const float4* s4 = (const float4*)src;

  float4 x[5];
  float m = -INFINITY;
#pragma unroll
  for (int k = 0; k < 5; ++k) {
    int c = tid + 256 * k;
    if (c < NC4) {
      x[k] = s4[c];
      m = fmaxf(m, fmaxf(fmaxf(x[k].x, x[k].y), fmaxf(x[k].z, x[k].w)));
    }
  }
#pragma unroll
  for (int j = 1; j < 64; j <<= 1) m = fmaxf(m, __shfl_xor(m, j, 64));
  if ((tid & 63) == 0) sm[tid >> 6] = m;
  __syncthreads();
  m = fmaxf(fmaxf(sm[0], sm[1]), fmaxf(sm[2], sm[3]));
  __syncthreads();

  float ssum = 0.f;
#pragma unroll
  for (int k = 0; k < 5; ++k) {
    int c = tid + 256 * k;
    if (c < NC4) {
      ssum += expf(x[k].x - m);
      ssum += expf(x[k].y - m);
      ssum += expf(x[k].z - m);
      ssum += expf(x[k].w - m);
    }
  }
#pragma unroll
  for (int j = 1; j < 64; j <<= 1) ssum += __shfl_xor(ssum, j, 64);
  if ((tid & 63) == 0) sm[4 + (tid >> 6)] = ssum;
  __syncthreads();
  ssum = (sm[4] + sm[5]) + (sm[6] + sm[7]);
  const float logS = logf(ssum);

  if (!build) {
    if (tid == 0) {
      if (is_lm) ((float4*)(ws + OFF_LSTAT4))[row] = make_float4(m, logS, __int_as_float(0), 0.f);
      else { ws[OFF_AM + t] = m; ws[OFF_ALS + t] = logS; }
    }
    return;
  }
  if (!is_lm && tid == 0) { ws[OFF_AM + t] = m; ws[OFF_ALS + t] = logS; }

  hist[tid] = 0;
  __syncthreads();
#pragma unroll
  for (int k = 0; k < 5; ++k) {
    int c = tid + 256 * k;
    if (c < NC4) {
      float vv[4] = {x[k].x, x[k].y, x[k].z, x[k].w};
#pragma unroll
      for (int j = 0; j < 4; ++j) atomicAdd(&hist[bin16(m, vv[j])], 1);
    }
  }
  __syncthreads();
  if (tid == 0) {
    int c = 0, bsel = 0;
    for (; bsel < 256; ++bsel) {
      int nc = c + hist[bsel];
      if (nc <= LK) c = nc; else break;
    }
    s_bsel = bsel;
    s_cnt = 0;
  }
  __syncthreads();
  const int bsel = s_bsel;
  const float wgt = is_lm ? WLM : WASR;
  float2* Llists = (float2*)(ws + OFF_LISTS);
  float2* dst = is_lm ? (Llists + (size_t)row * LK)
                      : (Llists + (size_t)VV * LK + (size_t)t * LK);
#pragma unroll
  for (int k = 0; k < 5; ++k) {
    int c = tid + 256 * k;
    if (c < NC4) {
      float vv[4] = {x[k].x, x[k].y, x[k].z, x[k].w};
#pragma unroll
      for (int j = 0; j < 4; ++j) {
        if (bin16(m, vv[j]) < bsel) {
          int p = atomicAdd(&s_cnt, 1);
          if (p < LK) {
            float sv = __fmul_rn(wgt, __fsub_rn(__fsub_rn(vv[j], m), logS));
            dst[p] = make_float2(sv, __int_as_float(c * 4 + j));
          }
        }
      }
    }
  }
  __syncthreads();
  const int cnt = s_cnt;
  const bool ovf = (cnt == 0);
  for (int p = cnt + tid; p < LK; p += 256)
    dst[p] = make_float2(-1e30f, __int_as_float(0x7FFFFFFF));

  if (tid == 0) {
    float theta = __fsub_rn(m, (float)bsel * 0.0625f);
    float bnd = ovf ? INFINITY : __fmul_rn(wgt, __fsub_rn(__fsub_rn(theta, m), logS));
    int bselO = ovf ? 0 : bsel;
    if (is_lm) ((float4*)(ws + OFF_LSTAT4))[row] = make_float4(m, logS, __int_as_float(bselO), bnd);
    else { ws[OFF_ATH + t] = __int_as_float(bselO); ws[OFF_ABND + t] = bnd; }
  }
}

// ---------------- multi-WG beam search: tagged-pair all-to-all exchange ----------
__global__ __launch_bounds__(256) void beam_mw(
    const float* __restrict__ asr, const float* __restrict__ lm,
    float* __restrict__ ws, float* __restrict__ out)
{
  const int b   = (int)blockIdx.x;
  const int tid = (int)threadIdx.x;
  const int lane = tid & 63;
  const int w = tid >> 6;

  const float2* __restrict__ Llists = (const float2*)(ws + OFF_LISTS);
  const float2* __restrict__ Alists = Llists + (size_t)VV * LK;
  const float4* __restrict__ lstat4 = (const float4*)(ws + OFF_LSTAT4);
  unsigned long long* D = (unsigned long long*)(ws + OFF_COMM);

  __shared__ float s_cv[FCAP];
  __shared__ int   s_ct[FCAP];
  __shared__ unsigned long long s_key[256];
  __shared__ unsigned long long s_k2[64];
  __shared__ float s_sv2[64];
  __shared__ int   s_si2[64];
  __shared__ float s_selv[BEAMW];
  __shared__ int   s_seli[BEAMW];
  __shared__ float s_ftau[4];
  __shared__ int   s_fcnt;
  __shared__ int   s_redo;
  __shared__ unsigned short s_toks[TT * BEAMW];   // beam-0 WG only
  __shared__ unsigned char  s_bps[TT * BEAMW];

  float s = (b == 0) ? 0.0f : -1e30f;
  int last = SOS_TOK;
  float4 lst = lstat4[SOS_TOK];

  // local merge of 256 pooled survivors (s_cv/s_ct) -> s_selv/s_seli
  auto merge256 = [&]() {
    float v = s_cv[tid]; int fl = s_ct[tid];
    unsigned long long key = ((unsigned long long)fkey(v) << 17) | (unsigned)(131071 - fl);
    s_key[tid] = key;
    __syncthreads();
    int segbase = tid & ~63;
    int r = 0;
    for (int j = 0; j < 64; ++j) r += (s_key[segbase + j] > key) ? 1 : 0;
    if (r < BEAMW) {
      int slot = ((tid >> 6) << 4) | r;
      s_k2[slot] = key; s_sv2[slot] = v; s_si2[slot] = fl;
    }
    __syncthreads();
    if (tid < 64) {
      unsigned long long k2 = s_k2[tid];
      int r2 = 0;
      for (int j = 0; j < 64; ++j) r2 += (s_k2[j] > k2) ? 1 : 0;
      if (r2 < BEAMW) { s_selv[r2] = s_sv2[tid]; s_seli[r2] = s_si2[tid]; }
    }
    __syncthreads();
  };

  for (int t = 0; t < TT; ++t) {
    const float am   = ws[OFF_AM + t];
    const float als  = ws[OFF_ALS + t];
    const float abnd = ws[OFF_ABND + t];
    const float mB = lst.x, lsB = lst.y, lbnd = lst.w;
    const int bselL = __float_as_int(lst.z);
    const float bound = __fadd_rn(__fadd_rn(s, abnd), lbnd) + 1e-3f;
    const unsigned long long want = (unsigned long long)(t + 1);
    const int par = t & 1;
    unsigned long long* P1 = D + 64   + par * 512;   // [b*32 + k]
    unsigned long long* RD = D + 1088 + par * 512;

    // ---- EVAL: 256 candidate slots (A: 0..127, L: 128..255) ----
    {
      float cv = -INFINITY; int ct = 0;
      int j = ((w & 1) << 6) | lane;
      if (w < 2) {
        float2 ae = Alists[(size_t)t * LK + j];
        int tok = __float_as_int(ae.y);
        bool valid = (ae.x > -9e29f);
        float xr = lm[(size_t)last * VV + (valid ? tok : 0)];
        if (valid) {
          ct = tok;
          bool inL = (bin16(mB, xr) < bselL);   // dedupe: token also in L-list
          if (!inL) {
            float svr = __fmul_rn(WLM, __fsub_rn(__fsub_rn(xr, mB), lsB));
            cv = __fadd_rn(__fadd_rn(s, ae.x), svr);
          }
        }
      } else {
        float2 le = Llists[(size_t)last * LK + j];
        int tok = __float_as_int(le.y);
        bool valid = (le.x > -9e29f);
        float ar = asr[(size_t)t * VV + (valid ? tok : 0)];
        if (valid) {
          ct = tok;
          float avr = __fmul_rn(WASR, __fsub_rn(__fsub_rn(ar, am), als));
          cv = __fadd_rn(__fadd_rn(s, avr), le.x);
        }
      }
      s_cv[tid] = cv; s_ct[tid] = ct;
    }
    __syncthreads();

    // ---- per-beam exact top-16 of 256 (two-stage rank) ----
    {
      float v = s_cv[tid]; int tok = s_ct[tid];
      bool inval = !(v > -INFINITY);
      int tkk = inval ? (5000 + tid) : tok;
      unsigned long long key = ((unsigned long long)fkey(v) << 13) | (unsigned)(8191 - tkk);
      s_key[tid] = key;
      __syncthreads();
      int segbase = tid & ~63;
      int r = 0;
      for (int j = 0; j < 64; ++j) r += (s_key[segbase + j] > key) ? 1 : 0;
      if (r < BEAMW) {
        int slot = ((tid >> 6) << 4) | r;
        s_k2[slot] = key; s_sv2[slot] = v; s_si2[slot] = inval ? -1 : tok;
      }
      __syncthreads();
      if (tid < 64) {
        unsigned long long k2 = s_k2[tid];
        int r2 = 0;
        for (int j = 0; j < 64; ++j) r2 += (s_k2[j] > k2) ? 1 : 0;
        if (r2 < BEAMW) {
          int tk2 = s_si2[tid];
          s_selv[r2] = s_sv2[tid];
          s_seli[r2] = (tk2 < 0) ? (80000 + b * BEAMW + r2) : (b * VV + tk2);
        }
      }
      __syncthreads();
    }

    // ---- publish: 16 tagged pairs + 1 tagged bound word (parallel stores) ----
    if (tid < BEAMW) {
      unsigned long long pk = (want << 54)
        | ((unsigned long long)(unsigned int)(s_seli[tid] & 0x3FFFFF) << 32)
        | (unsigned long long)__float_as_uint(s_selv[tid]);
      __hip_atomic_store(&P1[b * 32 + tid], pk, __ATOMIC_RELAXED, __HIP_MEMORY_SCOPE_AGENT);
    } else if (tid == BEAMW) {
      unsigned long long bk = (want << 54) | (unsigned long long)__float_as_uint(bound);
      __hip_atomic_store(&P1[b * 32 + 16], bk, __ATOMIC_RELAXED, __HIP_MEMORY_SCOPE_AGENT);
    }

    // ---- all-to-all read: each thread spins on its (q,k) pair ----
    {
      int q = tid >> 4, k = tid & 15;
      unsigned long long pk;
      int gd = 0;
      for (;;) {
        pk = __hip_atomic_load(&P1[q * 32 + k], __ATOMIC_RELAXED, __HIP_MEMORY_SCOPE_AGENT);
        if ((unsigned)(pk >> 54) == (unsigned)want) break;
        __builtin_amdgcn_s_sleep(1);
        if (++gd > 4000000) break;
      }
      s_cv[tid] = __uint_as_float((unsigned int)pk);
      s_ct[tid] = (int)((pk >> 32) & 0x3FFFFF);
    }
    __syncthreads();
    merge256();

    // ---- redundant redo decision (tagged bound words) ----
    {
      float tau16 = s_selv[BEAMW - 1];
      bool c16 = false;
      if (tid < BEAMW) {
        unsigned long long bk;
        int gd = 0;
        for (;;) {
          bk = __hip_atomic_load(&P1[tid * 32 + 16], __ATOMIC_RELAXED, __HIP_MEMORY_SCOPE_AGENT);
          if ((unsigned)(bk >> 54) == (unsigned)want) break;
          __builtin_amdgcn_s_sleep(1);
          if (++gd > 4000000) break;
        }
        c16 = (__uint_as_float((unsigned int)bk) > tau16);
      }
      unsigned long long mk = __ballot(c16);
      if (tid == 0) s_redo = (mk != 0ull) ? 1 : 0;
    }
    __syncthreads();

    // ---- rare: exact per-beam full scan + re-merge via tagged redo slots ----
    if (s_redo) {
      if (tid == 0) s_fcnt = 0;
      const float4* A4 = (const float4*)(asr + (size_t)t * VV);
      const float4* L4 = (const float4*)(lm + (size_t)last * VV);
      float chm[5]; float tm = -INFINITY;
#pragma unroll
      for (int q = 0; q < 5; ++q) {
        int c = tid + (q << 8);
        float cm = -INFINITY;
        if (c < NC4) {
          float4 a4 = A4[c]; float4 l4 = L4[c];
          float v0 = cand_val(s, a4.x, am, als, l4.x, mB, lsB);
          float v1 = cand_val(s, a4.y, am, als, l4.y, mB, lsB);
          float v2 = cand_val(s, a4.z, am, als, l4.z, mB, lsB);
          float v3 = cand_val(s, a4.w, am, als, l4.w, mB, lsB);
          cm = fmaxf(fmaxf(v0, v1), fmaxf(v2, v3));
        }
        chm[q] = cm; tm = fmaxf(tm, cm);
      }
      float vs = bitonic64_desc_val(tm, lane);
      if (lane == 15) s_ftau[w] = vs;
      __syncthreads();
      float tg = fmaxf(fmaxf(s_ftau[0], s_ftau[1]), fmaxf(s_ftau[2], s_ftau[3]));
#pragma unroll
      for (int q = 0; q < 5; ++q) {
        if (chm[q] >= tg) {
          int c = tid + (q << 8);
          float4 a4 = A4[c]; float4 l4 = L4[c];
          float ar4[4] = {a4.x, a4.y, a4.z, a4.w};
          float lr4[4] = {l4.x, l4.y, l4.z, l4.w};
#pragma unroll
          for (int i = 0; i < 4; ++i) {
            float v = cand_val(s, ar4[i], am, als, lr4[i], mB, lsB);
            if (v >= tg) {
              int p = atomicAdd(&s_fcnt, 1);
              if (p < FCAP) { s_cv[p] = v; s_ct[p] = c * 4 + i; }
            }
          }
        }
      }
      __syncthreads();
      int n = s_fcnt; if (n > FCAP) n = FCAP;
      {
        float v0 = (tid < n) ? s_cv[tid] : -INFINITY;
        int   t0 = (tid < n) ? s_ct[tid] : 0;
        float v1 = (tid + 256 < n) ? s_cv[tid + 256] : -INFINITY;
        int   t1 = (tid + 256 < n) ? s_ct[tid + 256] : 0;
        unsigned long long k0 = ((unsigned long long)fkey(v0) << 13) | (unsigned)(8191 - t0);
        unsigned long long k1 = ((unsigned long long)fkey(v1) << 13) | (unsigned)(8191 - t1);
        int r0 = 0, r1 = 0;
        for (int j = 0; j < n; ++j) {
          unsigned long long kj = ((unsigned long long)fkey(s_cv[j]) << 13) | (unsigned)(8191 - s_ct[j]);
          r0 += (kj > k0) ? 1 : 0;
          r1 += (kj > k1) ? 1 : 0;
        }
        __syncthreads();
        if (tid < n && r0 < BEAMW)       { s_selv[r0] = v0; s_seli[r0] = b * VV + t0; }
        if (tid + 256 < n && r1 < BEAMW) { s_selv[r1] = v1; s_seli[r1] = b * VV + t1; }
      }
      __syncthreads();

      if (tid < BEAMW) {
        unsigned long long pk = (want << 54)
          | ((unsigned long long)(unsigned int)(s_seli[tid] & 0x3FFFFF) << 32)
          | (unsigned long long)__float_as_uint(s_selv[tid]);
        __hip_atomic_store(&RD[b * 32 + tid], pk, __ATOMIC_RELAXED, __HIP_MEMORY_SCOPE_AGENT);
      }
      {
        int q = tid >> 4, k = tid & 15;
        unsigned long long pk;
        int gd = 0;
        for (;;) {
          pk = __hip_atomic_load(&RD[q * 32 + k], __ATOMIC_RELAXED, __HIP_MEMORY_SCOPE_AGENT);
          if ((unsigned)(pk >> 54) == (unsigned)want) break;
          __builtin_amdgcn_s_sleep(1);
          if (++gd > 4000000) break;
        }
        s_cv[tid] = __uint_as_float((unsigned int)pk);
        s_ct[tid] = (int)((pk >> 32) & 0x3FFFFF);
      }
      __syncthreads();
      merge256();
    }

    // ---- next state (each WG local) + beam-0 history ----
    if (b == 0 && tid < BEAMW) {
      int fl = s_seli[tid];
      int bp = fl / VV; int tok = fl - bp * VV;
      s_toks[t * BEAMW + tid] = (unsigned short)tok;
      s_bps[t * BEAMW + tid]  = (unsigned char)bp;
    }
    {
      float nv = s_selv[b]; int fl = s_seli[b];
      int bp = fl / VV; int tok = fl - bp * VV;
      s = nv; last = tok;
    }
    lst = lstat4[last];
    __syncthreads();
  }

  // ---- output (beam-0 WG) ----
  if (b == 0 && tid < BEAMW) {
    out[tid] = s_selv[tid];
    int ptr = tid;
    for (int tt = TT - 1; tt >= 0; --tt) {
      int tok = (int)s_toks[tt * BEAMW + ptr];
      out[BEAMW + tid * TT + tt] = (float)tok;
      ptr = (int)s_bps[tt * BEAMW + ptr];
    }
  }
}

// ---------------- fallback: single-WG full-scan kernel (ws too small) ----
__global__ __launch_bounds__(1024, 4) void beam_slow(
    const float* __restrict__ asr, const float* __restrict__ lm,
    const float* __restrict__ ws, float* __restrict__ out)
{
  __shared__ float s_scores[BEAMW];
  __shared__ int   s_last[BEAMW];
  __shared__ float s_lmm[BEAMW], s_lmls[BEAMW];
  __shared__ float s_tau[BEAMW];
  __shared__ float s_bufval[FCAP];
  __shared__ int   s_bufidx[FCAP];
  __shared__ int   s_cnt;
  __shared__ unsigned short s_toks[TT * BEAMW];
  __shared__ unsigned char  s_bps[TT * BEAMW];

  const int tid = (int)threadIdx.x;
  const int lane = tid & 63;
  const int w = tid >> 6;
  const float4* __restrict__ lstat4 = (const float4*)(ws + OFF_LSTAT4);

  if (tid < BEAMW) {
    s_scores[tid] = (tid == 0) ? 0.0f : -1e30f;
    s_last[tid] = SOS_TOK;
    float4 st = lstat4[SOS_TOK];
    s_lmm[tid] = st.x; s_lmls[tid] = st.y;
  }
  if (tid == 0) s_cnt = 0;
  __syncthreads();

  for (int t = 0; t < TT; ++t) {
    const float s = s_scores[w];
    const float mB = s_lmm[w], lsB = s_lmls[w];
    const int lastb = s_last[w];
    const float am = ws[OFF_AM + t], als = ws[OFF_ALS + t];
    const float4* __restrict__ L4p = (const float4*)(lm + (size_t)lastb * VV);
    const float4* __restrict__ A4p = (const float4*)(asr + (size_t)t * VV);

    float chm[20]; float rowm = -INFINITY;
#pragma unroll
    for (int k = 0; k < 20; ++k) {
      int c = lane + 64 * k;
      bool ok = (c < NC4);
      int cc = ok ? c : 0;
      float4 A4 = A4p[cc]; float4 L4 = L4p[cc];
      float vx = cand_val(s, A4.x, am, als, L4.x, mB, lsB);
      float vy = cand_val(s, A4.y, am, als, L4.y, mB, lsB);
      float vz = cand_val(s, A4.z, am, als, L4.z, mB, lsB);
      float vw = cand_val(s, A4.w, am, als, L4.w, mB, lsB);
      float cm = fmaxf(fmaxf(vx, vy), fmaxf(vz, vw));
      if (!ok) cm = -INFINITY;
      chm[k] = cm; rowm = fmaxf(rowm, cm);
    }
    {
      float v = bitonic64_desc_val(rowm, lane);
      if (lane == 15) s_tau[w] = v;
    }
    if (tid == 0) s_cnt = 0;
    __syncthreads();

    float tg = s_tau[lane & 15];
#pragma unroll
    for (int j = 1; j <= 8; j <<= 1) tg = fmaxf(tg, __shfl_xor(tg, j, 64));

#pragma unroll
    for (int k = 0; k < 20; ++k) {
      if (chm[k] >= tg) {
        int c = lane + 64 * k;
        float4 A4 = A4p[c]; float4 L4 = L4p[c];
        float ar4[4] = {A4.x, A4.y, A4.z, A4.w};
        float lr4[4] = {L4.x, L4.y, L4.z, L4.w};
#pragma unroll
        for (int i = 0; i < 4; ++i) {
          float v = cand_val(s, ar4[i], am, als, lr4[i], mB, lsB);
          if (v >= tg) {
            int p = atomicAdd(&s_cnt, 1);
            if (p < FCAP) { s_bufval[p] = v; s_bufidx[p] = w * VV + c * 4 + i; }
          }
        }
      }
    }
    __syncthreads();

    if (w == 0) {
      int n = s_cnt; if (n > FCAP) n = FCAP;
      if (n <= 64) {
        float bv = (lane < n) ? s_bufval[lane] : -INFINITY;
        int   bi = (lane < n) ? s_bufidx[lane] : 0x7FFFFFFF;
        bitonic64_desc_pair(bv, bi, lane);
        if (lane < BEAMW) {
          int flat = bi;
          int bb = flat / VV; int tok = flat - bb * VV;
          float4 st = lstat4[tok];
          s_scores[lane] = bv; s_last[lane] = tok;
          s_lmm[lane] = st.x; s_lmls[lane] = st.y;
          s_toks[t * BEAMW + lane] = (unsigned short)tok;
          s_bps[t * BEAMW + lane] = (unsigned char)bb;
        }
      } else {
        float pv = -INFINITY; int pi = 0x7FFFFFFF;
        for (int it = 0; it < BEAMW; ++it) {
          float cvv = -INFINITY; int cii = 0x7FFFFFFF;
          for (int k2 = 0; k2 < FCAP / 64; ++k2) {
            int p = lane + 64 * k2;
            if (p < n) {
              float vv2 = s_bufval[p]; int ii2 = s_bufidx[p];
              bool lessPrev = (it == 0) || (vv2 < pv) || (vv2 == pv && ii2 > pi);
              bool better = (vv2 > cvv) || (vv2 == cvv && ii2 < cii);
              if (lessPrev && better) { cvv = vv2; cii = ii2; }
            }
          }
          for (int j = 1; j < 64; j <<= 1) {
            float ov = __shfl_xor(cvv, j, 64); int oi = __shfl_xor(cii, j, 64);
            bool ob = (ov > cvv) || (ov == cvv && oi < cii);
            if (ob) { cvv = ov; cii = oi; }
          }
          if (lane == 0) {
            int bb = cii / VV; int tok = cii - bb * VV;
            float4 st = lstat4[tok];
            s_scores[it] = cvv; s_last[it] = tok;
            s_lmm[it] = st.x; s_lmls[it] = st.y;
            s_toks[t * BEAMW + it] = (unsigned short)tok;
            s_bps[t * BEAMW + it] = (unsigned char)bb;
          }
          pv = cvv; pi = cii;
        }
      }
    }
    __syncthreads();
  }

  if (tid < BEAMW) {
    out[tid] = s_scores[tid];
    int ptr = tid;
    for (int t = TT - 1; t >= 0; --t) {
      int tok = (int)s_toks[t * BEAMW + ptr];
      out[BEAMW + tid * TT + t] = (float)tok;
      ptr = (int)s_bps[t * BEAMW + ptr];
    }
  }
}

extern "C" void kernel_launch(void* const* d_in, const int* in_sizes, int n_in,
                              void* d_out, int out_size, void* d_ws, size_t ws_size,
                              hipStream_t stream) {
  const float* asr = (const float*)d_in[0];
  const float* lm  = (const float*)d_in[1];
  float* out = (float*)d_out;
  float* ws  = (float*)d_ws;

  int build = (ws_size >= ws_need_floats() * sizeof(float)) ? 1 : 0;
  hipLaunchKernelGGL(prep_kernel, dim3(VV + TT), dim3(256), 0, stream, asr, lm, ws, build);
  if (build)
    hipLaunchKernelGGL(beam_mw, dim3(BEAMW), dim3(256), 0, stream, asr, lm, ws, out);
  else
    hipLaunchKernelGGL(beam_slow, dim3(1), dim3(1024), 0, stream, asr, lm, ws, out);
}